// Round 9
// baseline (70.451 us; speedup 1.0000x reference)
//
#include <hip/hip_runtime.h>
#include <cmath>

#define D 4096

typedef float fvec4 __attribute__((ext_vector_type(4)));

__device__ __forceinline__ float wave_reduce_sum(float v) {
#pragma unroll
    for (int off = 32; off > 0; off >>= 1)
        v += __shfl_down(v, off, 64);
    return v;
}

__device__ __forceinline__ float sigmoidf(float x) {
    return 1.0f / (1.0f + expf(-x));
}

// ws layout (floats):
//   [0 .. 4095]   q
//   [4096 .. 8191] k (already scaled by 1/sqrt(D))
//   [16384]       raw i dot (w_i@x + b_i)
//   [16385]       raw f dot (w_f@x + b_f)

// Kernel 1: q,k matvecs (128 MB weight reads) + i/f dots.
// One row of wq AND one row of wk per wave (interleaved load streams).
__global__ __launch_bounds__(256) void qk_kernel(
    const float* __restrict__ x,
    const float* __restrict__ wq, const float* __restrict__ bq,
    const float* __restrict__ wk, const float* __restrict__ bk,
    const float* __restrict__ wi, const float* __restrict__ bi,
    const float* __restrict__ wf, const float* __restrict__ bfv,
    float* __restrict__ ws)
{
    __shared__ float xs[D];
    const int tid = threadIdx.x;
    fvec4* xs4 = (fvec4*)xs;
    const fvec4* x4 = (const fvec4*)x;
#pragma unroll
    for (int i = 0; i < 4; ++i) xs4[tid + i * 256] = x4[tid + i * 256];
    __syncthreads();

    const int wave = tid >> 6;
    const int lane = tid & 63;

    if (blockIdx.x == 1024) {
        if (wave < 2) {
            const fvec4* W4 = (const fvec4*)(wave == 0 ? wi : wf);
            float acc = 0.f;
#pragma unroll
            for (int it = 0; it < 16; ++it) {
                fvec4 w = W4[it * 64 + lane];
                fvec4 xv = xs4[it * 64 + lane];
                acc += w.x * xv.x + w.y * xv.y + w.z * xv.z + w.w * xv.w;
            }
            acc = wave_reduce_sum(acc);
            if (lane == 0) {
                float b = (wave == 0) ? bi[0] : bfv[0];
                ws[16384 + wave] = acc + b;
            }
        }
        return;
    }

    const int row = blockIdx.x * 4 + wave;         // [0, 4096)
    const fvec4* Wq4 = (const fvec4*)(wq + (size_t)row * D);
    const fvec4* Wk4 = (const fvec4*)(wk + (size_t)row * D);
    float aq0 = 0.f, aq1 = 0.f, ak0 = 0.f, ak1 = 0.f;
#pragma unroll
    for (int it = 0; it < 16; it += 2) {
        fvec4 q0 = Wq4[it * 64 + lane];
        fvec4 q1 = Wq4[(it + 1) * 64 + lane];
        fvec4 k0 = Wk4[it * 64 + lane];
        fvec4 k1 = Wk4[(it + 1) * 64 + lane];
        fvec4 xv0 = xs4[it * 64 + lane];
        fvec4 xv1 = xs4[(it + 1) * 64 + lane];
        aq0 += q0.x * xv0.x + q0.y * xv0.y + q0.z * xv0.z + q0.w * xv0.w;
        aq1 += q1.x * xv1.x + q1.y * xv1.y + q1.z * xv1.z + q1.w * xv1.w;
        ak0 += k0.x * xv0.x + k0.y * xv0.y + k0.z * xv0.z + k0.w * xv0.w;
        ak1 += k1.x * xv1.x + k1.y * xv1.y + k1.z * xv1.z + k1.w * xv1.w;
    }
    float accq = wave_reduce_sum(aq0 + aq1);
    float acck = wave_reduce_sum(ak0 + ak1);
    if (lane == 0) {
        ws[row]        = accq + bq[row];
        ws[4096 + row] = (acck + bk[row]) * 0.015625f;   // 1/sqrt(4096)
    }
}

// Kernel 2: fused v/o matvecs + cell stream + h/n epilogue.
// LDS time-multiplexed in ONE 32 KB buffer (4 blocks/CU residency):
//   phase A: lo = x, hi = k   -> v,o matvecs (read lo)
//   phase B: lo = q (restage) -> kq/npq dots, cell stream (read lo,hi)
__global__ __launch_bounds__(256) void vocell_kernel(
    const float* __restrict__ x,
    const float* __restrict__ c_prev,
    const float* __restrict__ n_prev,
    const float* __restrict__ wv, const float* __restrict__ bv,
    const float* __restrict__ wo, const float* __restrict__ bo,
    const float* __restrict__ ws,
    float* __restrict__ c_out,
    float* __restrict__ out)
{
    __shared__ float sbuf[2 * D];
    __shared__ float red[8];
    const int tid = threadIdx.x;
    const int wave = tid >> 6;
    const int lane = tid & 63;

    fvec4* lo4 = (fvec4*)sbuf;           // x, later q
    fvec4* hi4 = (fvec4*)(sbuf + D);     // k throughout
    const fvec4* x4  = (const fvec4*)x;
    const fvec4* q4g = (const fvec4*)ws;
    const fvec4* k4g = (const fvec4*)(ws + D);
    const fvec4* np4 = (const fvec4*)n_prev;

#pragma unroll
    for (int i = 0; i < 4; ++i) {
        int j = tid + i * 256;
        lo4[j] = x4[j];
        hi4[j] = k4g[j];
    }
    __syncthreads();

    const int row = blockIdx.x * 4 + wave;           // [0, 4096)

    // ---- phase A: v,o matvecs for this wave's row (reads lo = x) ----
    const fvec4* Wv4 = (const fvec4*)(wv + (size_t)row * D);
    const fvec4* Wo4 = (const fvec4*)(wo + (size_t)row * D);
    float av0 = 0.f, av1 = 0.f, ao0 = 0.f, ao1 = 0.f;
#pragma unroll
    for (int it = 0; it < 16; it += 2) {
        fvec4 v0 = Wv4[it * 64 + lane];
        fvec4 v1 = Wv4[(it + 1) * 64 + lane];
        fvec4 o0 = Wo4[it * 64 + lane];
        fvec4 o1 = Wo4[(it + 1) * 64 + lane];
        fvec4 xv0 = lo4[it * 64 + lane];
        fvec4 xv1 = lo4[(it + 1) * 64 + lane];
        av0 += v0.x * xv0.x + v0.y * xv0.y + v0.z * xv0.z + v0.w * xv0.w;
        av1 += v1.x * xv1.x + v1.y * xv1.y + v1.z * xv1.z + v1.w * xv1.w;
        ao0 += o0.x * xv0.x + o0.y * xv0.y + o0.z * xv0.z + o0.w * xv0.w;
        ao1 += o1.x * xv1.x + o1.y * xv1.y + o1.z * xv1.z + o1.w * xv1.w;
    }
    float v = wave_reduce_sum(av0 + av1);
    float o = wave_reduce_sum(ao0 + ao1);
    v = __shfl(v, 0) + bv[row];                      // broadcast to all lanes
    o = sigmoidf(__shfl(o, 0) + bo[row]);

    // ---- restage lo = q ----
    __syncthreads();                                 // all done reading x
#pragma unroll
    for (int i = 0; i < 4; ++i) {
        int j = tid + i * 256;
        lo4[j] = q4g[j];
    }
    __syncthreads();

    // block-redundant kq = k.q, npq = n_prev.q (identical fp32 everywhere)
    float kq = 0.f, npq = 0.f;
#pragma unroll
    for (int i = 0; i < 4; ++i) {
        int j = tid + i * 256;
        fvec4 q = lo4[j], k = hi4[j], np = np4[j];
        kq  += k.x * q.x + k.y * q.y + k.z * q.z + k.w * q.w;
        npq += np.x * q.x + np.y * q.y + np.z * q.z + np.w * q.w;
    }
    kq = wave_reduce_sum(kq);
    npq = wave_reduce_sum(npq);
    if (lane == 0) { red[wave] = kq; red[4 + wave] = npq; }
    __syncthreads();
    kq  = (red[0] + red[1]) + (red[2] + red[3]);
    npq = (red[4] + red[5]) + (red[6] + red[7]);

    const float i_t = expf(ws[16384]);
    const float f_t = sigmoidf(ws[16385]);
    const float nqt = f_t * npq + i_t * kq;          // n_t . q
    const float inv = 1.0f / fmaxf(fabsf(nqt), 1.0f);

    // ---- cell stream for this row ----
    const float vr = v * i_t;
    const fvec4* cp4 = (const fvec4*)(c_prev + (size_t)row * D);
    fvec4* co4 = (fvec4*)(c_out + (size_t)row * D);
    float dot = 0.f;
#pragma unroll
    for (int it = 0; it < 16; ++it) {
        int j = it * 64 + lane;
        fvec4 cp = __builtin_nontemporal_load(&cp4[j]);
        fvec4 kk = hi4[j];
        fvec4 qq = lo4[j];
        fvec4 ct;
        ct.x = f_t * cp.x + vr * kk.x;
        ct.y = f_t * cp.y + vr * kk.y;
        ct.z = f_t * cp.z + vr * kk.z;
        ct.w = f_t * cp.w + vr * kk.w;
        __builtin_nontemporal_store(ct, &co4[j]);
        dot += cp.x * qq.x + cp.y * qq.y + cp.z * qq.z + cp.w * qq.w;
    }
    dot = wave_reduce_sum(dot);
    if (lane == 0) {
        out[row] = o * (f_t * dot + i_t * kq * v) * inv;   // h_t
    }

    // n_t rows of this block (full k vector staged in hi)
    if (tid < 4) {
        const int idx = blockIdx.x * 4 + tid;
        out[(size_t)4096 + (size_t)D * D + idx] = f_t * n_prev[idx] + i_t * sbuf[D + idx];
    }
}

extern "C" void kernel_launch(void* const* d_in, const int* in_sizes, int n_in,
                              void* d_out, int out_size, void* d_ws, size_t ws_size,
                              hipStream_t stream)
{
    const float* x      = (const float*)d_in[0];
    const float* c_prev = (const float*)d_in[1];
    const float* n_prev = (const float*)d_in[2];
    const float* wq = (const float*)d_in[3];  const float* bq  = (const float*)d_in[4];
    const float* wk = (const float*)d_in[5];  const float* bk  = (const float*)d_in[6];
    const float* wv = (const float*)d_in[7];  const float* bv  = (const float*)d_in[8];
    const float* wi = (const float*)d_in[9];  const float* bi  = (const float*)d_in[10];
    const float* wf = (const float*)d_in[11]; const float* bfv = (const float*)d_in[12];
    const float* wo = (const float*)d_in[13]; const float* bo  = (const float*)d_in[14];
    float* out = (float*)d_out;
    float* ws  = (float*)d_ws;

    qk_kernel<<<dim3(1025), dim3(256), 0, stream>>>(
        x, wq, bq, wk, bk, wi, bi, wf, bfv, ws);
    vocell_kernel<<<dim3(1024), dim3(256), 0, stream>>>(
        x, c_prev, n_prev, wv, bv, wo, bo, ws, out + D, out);
}